// Round 8
// baseline (324.592 us; speedup 1.0000x reference)
//
#include <hip/hip_runtime.h>

#define N_NODES 50000
#define N_EDGES 800000
#define DIM 128
#define NB 196          // buckets of 256 nodes
#define CHUNK 4096      // edges per block chunk (196*4096 >= 800000)
#define GRID 196        // persistent build grid: 1 block/CU, trivially co-resident
#define SEG_CAP 6144    // LDS csr segment cap (mean 4096, sigma 64)

// ---------------- bf16 pack/unpack (RNE) ----------------

__device__ inline unsigned pk_bf16(float a, float b) {
    unsigned ua = __float_as_uint(a); ua = (ua + 0x7FFFu + ((ua >> 16) & 1u)) >> 16;
    unsigned ub = __float_as_uint(b); ub = (ub + 0x7FFFu + ((ub >> 16) & 1u)) >> 16;
    return ua | (ub << 16);
}
__device__ inline float bf_lo(unsigned u) { return __uint_as_float(u << 16); }
__device__ inline float bf_hi(unsigned u) { return __uint_as_float(u & 0xFFFF0000u); }

// ---------------- device-wide barrier (GRID blocks co-resident) ----------------

__device__ inline void gbarrier(int* cnt, int phase) {
    __syncthreads();
    if (threadIdx.x == 0) {
        __threadfence();
        __hip_atomic_fetch_add(cnt + phase, 1, __ATOMIC_ACQ_REL, __HIP_MEMORY_SCOPE_AGENT);
        while (__hip_atomic_load(cnt + phase, __ATOMIC_ACQUIRE, __HIP_MEMORY_SCOPE_AGENT) < GRID)
            __builtin_amdgcn_s_sleep(4);
        __threadfence();
    }
    __syncthreads();
}

union BuildLDS {                 // phase-exclusive big LDS buffer
    unsigned sl[CHUNK];          // P3 sort staging (16 KB)
    int seg[SEG_CAP];            // P4 csr segment (24 KB)
    float xs[64][128];           // P5 gemm tile (32 KB)
};

// ---- fused: chunk-hist -> offsets -> sort -> per-bucket CSR -> gemm1 ----
// No global atomics anywhere: run offsets derived from the chist matrix.

__global__ __launch_bounds__(256) void build_kernel(
        const int* __restrict__ src, const int* __restrict__ dst,
        const float* __restrict__ x, const float* __restrict__ W1,
        int* __restrict__ barcnt, int* __restrict__ chist,
        int* __restrict__ rowptr, float* __restrict__ dinv,
        unsigned* __restrict__ sorted, int* __restrict__ csr,
        uint2* __restrict__ hp) {
    __shared__ int hist[256], sc[256], aux[256], gbase[256],
                   lbase[256], lcur[256], bbase_s[256], cnt_s[256];
    __shared__ BuildLDS u;
    const int t = threadIdx.x;
    const int bid = blockIdx.x;
    const int eb = bid * CHUNK;
    const int ecnt = min(CHUNK, N_EDGES - eb);

    // ---- P1: LDS histogram of this chunk's dst buckets -> chist row ----
    hist[t] = 0;
    __syncthreads();
    for (int i = t; i < ecnt; i += 256)
        atomicAdd(&hist[dst[eb + i] >> 8], 1);
    __syncthreads();
    chist[bid * 256 + t] = hist[t];
    gbarrier(barcnt, 0);

    // ---- P2: bucket totals + bases + this block's run offset per bucket ----
    {
        int sum = 0, myoff = 0;
        for (int c = 0; c < GRID; ++c) {
            int v = chist[c * 256 + t];
            if (c == bid) myoff = sum;      // edges for bucket t in chunks < bid
            sum += v;
        }
        cnt_s[t] = sum;
        aux[t] = myoff;
        sc[t] = sum;
        __syncthreads();
        for (int off = 1; off < 256; off <<= 1) {
            int uu = (t >= off) ? sc[t - off] : 0;
            __syncthreads();
            sc[t] += uu;
            __syncthreads();
        }
        bbase_s[t] = sc[t] - cnt_s[t];      // bucket base (all blocks compute same)
        gbase[t] = bbase_s[t] + aux[t];     // this block's run start in bucket t
        if (bid == 0 && t == 0) rowptr[N_NODES] = N_EDGES;
    }

    // ---- P3: counting-sort chunk into LDS, write coalesced runs ----
    {
        sc[t] = hist[t];
        __syncthreads();
        for (int off = 1; off < 256; off <<= 1) {
            int uu = (t >= off) ? sc[t - off] : 0;
            __syncthreads();
            sc[t] += uu;
            __syncthreads();
        }
        int ex = sc[t] - hist[t];
        lbase[t] = ex;
        lcur[t] = ex;
        __syncthreads();
        for (int i = t; i < ecnt; i += 256) {
            int s = src[eb + i], d = dst[eb + i];
            int b = d >> 8;
            int p = atomicAdd(&lcur[b], 1);                 // LDS atomic
            u.sl[p] = ((unsigned)b << 24) | ((unsigned)(d & 255) << 16) | (unsigned)s;
        }
        __syncthreads();
        for (int i = t; i < ecnt; i += 256) {
            unsigned rec = u.sl[i];
            int b = rec >> 24;
            sorted[gbase[b] + (i - lbase[b])] = rec;        // coalesced runs
        }
    }
    gbarrier(barcnt, 1);

    // ---- P4: per-bucket CSR finalize (block bid = bucket bid) ----
    {
        const int base = bbase_s[bid];
        const int cntk = cnt_s[bid];
        hist[t] = 0;
        __syncthreads();
        for (int i = t; i < cntk; i += 256)
            atomicAdd(&hist[(sorted[base + i] >> 16) & 255], 1);
        __syncthreads();
        const int node = (bid << 8) + t;
        const int dv = hist[t];
        if (node < N_NODES) dinv[node] = rsqrtf((float)dv + 1.0f);   // +1 self-loop
        sc[t] = dv;
        __syncthreads();
        for (int off = 1; off < 256; off <<= 1) {
            int uu = (t >= off) ? sc[t - off] : 0;
            __syncthreads();
            sc[t] += uu;
            __syncthreads();
        }
        int ex = sc[t] - dv;
        if (node < N_NODES) rowptr[node] = base + ex;
        lcur[t] = ex;
        __syncthreads();
        if (cntk <= SEG_CAP) {
            for (int i = t; i < cntk; i += 256) {
                unsigned rec = sorted[base + i];
                int p = atomicAdd(&lcur[(rec >> 16) & 255], 1);
                u.seg[p] = (int)(rec & 0xFFFFu);
            }
            __syncthreads();
            for (int i = t; i < cntk; i += 256)
                csr[base + i] = u.seg[i];                   // coalesced
        } else {                                            // ~impossible fallback
            for (int i = t; i < cntk; i += 256) {
                unsigned rec = sorted[base + i];
                int p = atomicAdd(&lcur[(rec >> 16) & 255], 1);
                csr[base + p] = (int)(rec & 0xFFFFu);
            }
        }
    }
    gbarrier(barcnt, 2);

    // ---- P5: gemm1 tail: hp(bf16) = (x@W1)*dinv, grid-stride tiles ----
    const int ct = t & 31;
    const int rt = t >> 5;
    const float4* W4 = (const float4*)W1;
    for (int tile = bid; tile * 64 < N_NODES; tile += GRID) {
        const int rbase = tile * 64;
        __syncthreads();
        for (int idx = t; idx < 2048; idx += 256) {
            int r = idx >> 5, gr = rbase + r;
            float4 v = make_float4(0.f, 0.f, 0.f, 0.f);
            if (gr < N_NODES) v = ((const float4*)x)[(size_t)gr * 32 + (idx & 31)];
            ((float4*)u.xs)[idx] = v;
        }
        __syncthreads();

        float4 acc[8];
#pragma unroll
        for (int j = 0; j < 8; ++j) acc[j] = make_float4(0.f, 0.f, 0.f, 0.f);
        for (int k0 = 0; k0 < 128; k0 += 4) {
            float4 xk[8];
#pragma unroll
            for (int j = 0; j < 8; ++j)
                xk[j] = *(const float4*)&u.xs[rt * 8 + j][k0];
#pragma unroll
            for (int kk = 0; kk < 4; ++kk) {
                float4 w = W4[(k0 + kk) * 32 + ct];
#pragma unroll
                for (int j = 0; j < 8; ++j) {
                    float xv = (kk == 0) ? xk[j].x : (kk == 1) ? xk[j].y
                              : (kk == 2) ? xk[j].z : xk[j].w;
                    acc[j].x += xv * w.x;
                    acc[j].y += xv * w.y;
                    acc[j].z += xv * w.z;
                    acc[j].w += xv * w.w;
                }
            }
        }
#pragma unroll
        for (int j = 0; j < 8; ++j) {
            int r = rbase + rt * 8 + j;
            if (r < N_NODES) {
                float di = dinv[r];
                uint2 o;
                o.x = pk_bf16(acc[j].x * di, acc[j].y * di);
                o.y = pk_bf16(acc[j].z * di, acc[j].w * di);
                hp[(size_t)r * 32 + ct] = o;
            }
        }
    }
}

// ---------------- standalone GEMM (layer 2) ----------------

__global__ __launch_bounds__(256) void gemm_xw(const float* __restrict__ X,
                                               const float* __restrict__ W,
                                               const float* __restrict__ dinv,
                                               uint2* __restrict__ O, int nrows) {
    __shared__ float Xs[64][128];
    const int rbase = blockIdx.x * 64;
    const int t = threadIdx.x;

    for (int idx = t; idx < 2048; idx += 256) {
        int r = idx >> 5;
        int gr = rbase + r;
        float4 v = make_float4(0.f, 0.f, 0.f, 0.f);
        if (gr < nrows) v = ((const float4*)X)[(size_t)gr * 32 + (idx & 31)];
        ((float4*)Xs)[idx] = v;
    }
    __syncthreads();

    const int ct = t & 31;
    const int rt = t >> 5;
    float4 acc[8];
#pragma unroll
    for (int j = 0; j < 8; ++j) acc[j] = make_float4(0.f, 0.f, 0.f, 0.f);

    const float4* W4 = (const float4*)W;
    for (int k0 = 0; k0 < 128; k0 += 4) {
        float4 xk[8];
#pragma unroll
        for (int j = 0; j < 8; ++j)
            xk[j] = *(const float4*)&Xs[rt * 8 + j][k0];
#pragma unroll
        for (int kk = 0; kk < 4; ++kk) {
            float4 w = W4[(k0 + kk) * 32 + ct];
#pragma unroll
            for (int j = 0; j < 8; ++j) {
                float xv = (kk == 0) ? xk[j].x : (kk == 1) ? xk[j].y
                          : (kk == 2) ? xk[j].z : xk[j].w;
                acc[j].x += xv * w.x;
                acc[j].y += xv * w.y;
                acc[j].z += xv * w.z;
                acc[j].w += xv * w.w;
            }
        }
    }

#pragma unroll
    for (int j = 0; j < 8; ++j) {
        int r = rbase + rt * 8 + j;
        if (r < nrows) {
            float di = dinv[r];
            uint2 o;
            o.x = pk_bf16(acc[j].x * di, acc[j].y * di);
            o.y = pk_bf16(acc[j].z * di, acc[j].w * di);
            O[(size_t)r * 32 + ct] = o;
        }
    }
}

// ---------------- CSR aggregate (bf16 gather) ----------------

__global__ __launch_bounds__(256) void aggregate_kernel(const uint2* __restrict__ H2,
                                                        const int* __restrict__ rowptr,
                                                        const int* __restrict__ csr,
                                                        const float* __restrict__ dinv,
                                                        const float4* __restrict__ b4,
                                                        float4* __restrict__ out,
                                                        int relu) {
    int node = blockIdx.x * 4 + (threadIdx.x >> 6);
    if (node >= N_NODES) return;
    const int lane = threadIdx.x & 63;
    const int half = lane >> 5;
    const int col  = lane & 31;

    float4 acc = make_float4(0.f, 0.f, 0.f, 0.f);
    if (half == 0) {                      // self-loop term
        uint2 v = H2[(size_t)node * 32 + col];
        acc.x = bf_lo(v.x); acc.y = bf_hi(v.x);
        acc.z = bf_lo(v.y); acc.w = bf_hi(v.y);
    }

    int j = rowptr[node];
    const int end = rowptr[node + 1];

#define ACCUM(v) do { \
        acc.x += bf_lo((v).x); acc.y += bf_hi((v).x); \
        acc.z += bf_lo((v).y); acc.w += bf_hi((v).y); } while (0)

    for (; j + 16 <= end; j += 16) {
        int s0 = csr[j +  0 + half], s1 = csr[j +  2 + half];
        int s2 = csr[j +  4 + half], s3 = csr[j +  6 + half];
        int s4 = csr[j +  8 + half], s5 = csr[j + 10 + half];
        int s6 = csr[j + 12 + half], s7 = csr[j + 14 + half];
        uint2 v0 = H2[(size_t)s0 * 32 + col];
        uint2 v1 = H2[(size_t)s1 * 32 + col];
        uint2 v2 = H2[(size_t)s2 * 32 + col];
        uint2 v3 = H2[(size_t)s3 * 32 + col];
        uint2 v4 = H2[(size_t)s4 * 32 + col];
        uint2 v5 = H2[(size_t)s5 * 32 + col];
        uint2 v6 = H2[(size_t)s6 * 32 + col];
        uint2 v7 = H2[(size_t)s7 * 32 + col];
        ACCUM(v0); ACCUM(v1); ACCUM(v2); ACCUM(v3);
        ACCUM(v4); ACCUM(v5); ACCUM(v6); ACCUM(v7);
    }
    if (j + 8 <= end) {
        int s0 = csr[j + half], s1 = csr[j + 2 + half];
        int s2 = csr[j + 4 + half], s3 = csr[j + 6 + half];
        uint2 v0 = H2[(size_t)s0 * 32 + col];
        uint2 v1 = H2[(size_t)s1 * 32 + col];
        uint2 v2 = H2[(size_t)s2 * 32 + col];
        uint2 v3 = H2[(size_t)s3 * 32 + col];
        ACCUM(v0); ACCUM(v1); ACCUM(v2); ACCUM(v3);
        j += 8;
    }
    if (j + 4 <= end) {
        int s0 = csr[j + half], s1 = csr[j + 2 + half];
        uint2 v0 = H2[(size_t)s0 * 32 + col];
        uint2 v1 = H2[(size_t)s1 * 32 + col];
        ACCUM(v0); ACCUM(v1);
        j += 4;
    }
    if (j + 2 <= end) {
        int s = csr[j + half];
        uint2 v = H2[(size_t)s * 32 + col];
        ACCUM(v);
        j += 2;
    }
    if (j < end && half == 0) {
        int s = csr[j];
        uint2 v = H2[(size_t)s * 32 + col];
        ACCUM(v);
    }
#undef ACCUM

    acc.x += __shfl_xor(acc.x, 32, 64);
    acc.y += __shfl_xor(acc.y, 32, 64);
    acc.z += __shfl_xor(acc.z, 32, 64);
    acc.w += __shfl_xor(acc.w, 32, 64);

    if (half == 0) {
        float di = dinv[node];
        float4 bb = b4[col];
        float4 o;
        o.x = acc.x * di + bb.x;
        o.y = acc.y * di + bb.y;
        o.z = acc.z * di + bb.z;
        o.w = acc.w * di + bb.w;
        if (relu) {
            o.x = fmaxf(o.x, 0.f); o.y = fmaxf(o.y, 0.f);
            o.z = fmaxf(o.z, 0.f); o.w = fmaxf(o.w, 0.f);
        }
        out[(size_t)node * 32 + col] = o;
    }
}

// ---------------- launch ----------------

extern "C" void kernel_launch(void* const* d_in, const int* in_sizes, int n_in,
                              void* d_out, int out_size, void* d_ws, size_t ws_size,
                              hipStream_t stream) {
    const float* x  = (const float*)d_in[0];
    const int*   ei = (const int*)d_in[1];
    const float* W1 = (const float*)d_in[2];
    const float* b1 = (const float*)d_in[3];
    const float* W2 = (const float*)d_in[4];
    const float* b2 = (const float*)d_in[5];
    float* out = (float*)d_out;

    const int* src = ei;             // edge_index[0]
    const int* dst = ei + N_EDGES;   // edge_index[1]

    char* p = (char*)d_ws;
    int*      barcnt = (int*)p;              p += 1024;                        // 16 counters
    int*      chist  = (int*)p;              p += GRID * 256 * 4;              // 200 KB
    float*    dinv   = (float*)p;            p += ((N_NODES * 4 + 1023) & ~1023);
    int*      rowptr = (int*)p;              p += (((N_NODES + 1) * 4 + 1023) & ~1023);
    unsigned* sorted = (unsigned*)p;         p += ((N_EDGES * 4 + 1023) & ~1023);
    int*      csr    = (int*)p;              p += ((N_EDGES * 4 + 1023) & ~1023);
    uint2*    hp     = (uint2*)p;            p += (size_t)N_NODES * DIM * 2;   // bf16 table
    float*    bufB   = (float*)p;                                              // fp32 h1

    const int gemmBlocks = (N_NODES + 63) / 64;   // 782
    const int aggBlocks  = (N_NODES + 3) / 4;     // 12500

    // zero the grid-barrier counters only (64 B)
    hipMemsetAsync(barcnt, 0, 64, stream);

    // fused CSR build + layer-1 gemm (persistent 196-block kernel)
    build_kernel<<<GRID, 256, 0, stream>>>(src, dst, x, W1, barcnt, chist,
                                           rowptr, dinv, sorted, csr, hp);

    // layer 1 aggregate (+bias+relu) -> bufB (fp32)
    aggregate_kernel<<<aggBlocks, 256, 0, stream>>>(hp, rowptr, csr, dinv,
                                                    (const float4*)b1, (float4*)bufB, 1);

    // layer 2: gemm -> hp (bf16), aggregate (+bias) -> out
    gemm_xw<<<gemmBlocks, 256, 0, stream>>>(bufB, W2, dinv, hp, N_NODES);
    aggregate_kernel<<<aggBlocks, 256, 0, stream>>>(hp, rowptr, csr, dinv,
                                                    (const float4*)b2, (float4*)out, 0);
}

// Round 9
// 248.307 us; speedup vs baseline: 1.3072x; 1.3072x over previous
//
#include <hip/hip_runtime.h>

#define N_NODES 50000
#define N_EDGES 800000
#define DIM 128
#define NB 196          // buckets of 256 nodes
#define CHUNK 4096      // edges per chunk; 196*4096 >= 800000
#define GRID 196        // chunks == buckets == blocks for build passes
#define SEG_CAP 6144    // LDS csr segment cap (mean 4096, sigma 64)

// ---------------- bf16 pack/unpack (RNE) ----------------

__device__ inline unsigned pk_bf16(float a, float b) {
    unsigned ua = __float_as_uint(a); ua = (ua + 0x7FFFu + ((ua >> 16) & 1u)) >> 16;
    unsigned ub = __float_as_uint(b); ub = (ub + 0x7FFFu + ((ub >> 16) & 1u)) >> 16;
    return ua | (ub << 16);
}
__device__ inline float bf_lo(unsigned u) { return __uint_as_float(u << 16); }
__device__ inline float bf_hi(unsigned u) { return __uint_as_float(u & 0xFFFF0000u); }

// ---------------- Pass A: per-chunk bucket histogram -> chist[bid][*] ------

__global__ __launch_bounds__(256) void chunk_hist(const int* __restrict__ dst,
                                                  int* __restrict__ chist) {
    __shared__ int hist[256];
    const int t = threadIdx.x;
    const int eb = blockIdx.x * CHUNK;
    const int cnt = min(CHUNK, N_EDGES - eb);
    hist[t] = 0;
    __syncthreads();
    for (int i = t; i < cnt; i += 256)
        atomicAdd(&hist[dst[eb + i] >> 8], 1);
    __syncthreads();
    chist[blockIdx.x * 256 + t] = hist[t];
}

// ---------------- Pass B: counting sort; offsets derived from chist --------
// Deterministic, zero global atomics: run offset of chunk b in bucket k =
// bucket_base(k) + sum_{c<b} chist[c][k].

__global__ __launch_bounds__(256) void sort_scatter(const int* __restrict__ src,
                                                    const int* __restrict__ dst,
                                                    const int* __restrict__ chist,
                                                    unsigned* __restrict__ sorted) {
    __shared__ int hist[256], sc[256], lbase[256], lcur[256], gbase[256];
    __shared__ unsigned sl[CHUNK];
    const int t = threadIdx.x;
    const int bid = blockIdx.x;
    const int eb = bid * CHUNK;
    const int cnt = min(CHUNK, N_EDGES - eb);

    // column sums + this block's intra-bucket offset
    int sum = 0, myoff = 0;
    for (int c = 0; c < GRID; ++c) {
        int v = chist[c * 256 + t];
        if (c == bid) myoff = sum;
        sum += v;
    }
    hist[t] = chist[bid * 256 + t];      // own chunk histogram
    sc[t] = sum;
    __syncthreads();
    for (int off = 1; off < 256; off <<= 1) {      // scan bucket totals
        int u = (t >= off) ? sc[t - off] : 0;
        __syncthreads();
        sc[t] += u;
        __syncthreads();
    }
    gbase[t] = (sc[t] - sum) + myoff;    // global run start for bucket t
    __syncthreads();

    sc[t] = hist[t];                     // scan own hist -> local layout
    __syncthreads();
    for (int off = 1; off < 256; off <<= 1) {
        int u = (t >= off) ? sc[t - off] : 0;
        __syncthreads();
        sc[t] += u;
        __syncthreads();
    }
    int ex = sc[t] - hist[t];
    lbase[t] = ex;
    lcur[t] = ex;
    __syncthreads();

    for (int i = t; i < cnt; i += 256) { // LDS counting-sort scatter
        int s = src[eb + i], d = dst[eb + i];
        int b = d >> 8;
        int p = atomicAdd(&lcur[b], 1);
        sl[p] = ((unsigned)b << 24) | ((unsigned)(d & 255) << 16) | (unsigned)s;
    }
    __syncthreads();
    for (int i = t; i < cnt; i += 256) { // coalesced run writes
        unsigned rec = sl[i];
        int b = rec >> 24;
        sorted[gbase[b] + (i - lbase[b])] = rec;
    }
}

// ---------------- Pass C: per-bucket CSR finalize (block = bucket) ----------

__global__ __launch_bounds__(256) void csr_build(const unsigned* __restrict__ sorted,
                                                 const int* __restrict__ chist,
                                                 int* __restrict__ rowptr,
                                                 float* __restrict__ dinv,
                                                 int* __restrict__ csr) {
    __shared__ int hist[256], sc[256], lcur[256], bbase_s[256], cnt_s[256];
    __shared__ int seg[SEG_CAP];
    const int t = threadIdx.x;
    const int k = blockIdx.x;

    int sum = 0;                          // bucket totals from chist columns
    for (int c = 0; c < GRID; ++c) sum += chist[c * 256 + t];
    cnt_s[t] = sum;
    sc[t] = sum;
    __syncthreads();
    for (int off = 1; off < 256; off <<= 1) {
        int u = (t >= off) ? sc[t - off] : 0;
        __syncthreads();
        sc[t] += u;
        __syncthreads();
    }
    bbase_s[t] = sc[t] - cnt_s[t];
    __syncthreads();
    const int base = bbase_s[k];
    const int cntk = cnt_s[k];
    if (k == 0 && t == 0) rowptr[N_NODES] = N_EDGES;

    hist[t] = 0;
    __syncthreads();
    for (int i = t; i < cntk; i += 256)
        atomicAdd(&hist[(sorted[base + i] >> 16) & 255], 1);
    __syncthreads();

    const int node = (k << 8) + t;
    const int dv = hist[t];
    if (node < N_NODES) dinv[node] = rsqrtf((float)dv + 1.0f);   // +1 self-loop

    sc[t] = dv;
    __syncthreads();
    for (int off = 1; off < 256; off <<= 1) {
        int u = (t >= off) ? sc[t - off] : 0;
        __syncthreads();
        sc[t] += u;
        __syncthreads();
    }
    int ex = sc[t] - dv;
    if (node < N_NODES) rowptr[node] = base + ex;
    lcur[t] = ex;
    __syncthreads();

    if (cntk <= SEG_CAP) {
        for (int i = t; i < cntk; i += 256) {
            unsigned rec = sorted[base + i];
            int p = atomicAdd(&lcur[(rec >> 16) & 255], 1);
            seg[p] = (int)(rec & 0xFFFFu);
        }
        __syncthreads();
        for (int i = t; i < cntk; i += 256)
            csr[base + i] = seg[i];                  // coalesced, single-owner lines
    } else {                                         // ~impossible fallback
        for (int i = t; i < cntk; i += 256) {
            unsigned rec = sorted[base + i];
            int p = atomicAdd(&lcur[(rec >> 16) & 255], 1);
            csr[base + p] = (int)(rec & 0xFFFFu);
        }
    }
}

// ---------------- GEMM: hp[n,128](bf16) = (X[n,128] @ W[128,128]) * dinv ----

__global__ __launch_bounds__(256) void gemm_xw(const float* __restrict__ X,
                                               const float* __restrict__ W,
                                               const float* __restrict__ dinv,
                                               uint2* __restrict__ O, int nrows) {
    __shared__ float Xs[64][128];
    const int rbase = blockIdx.x * 64;
    const int t = threadIdx.x;

    for (int idx = t; idx < 2048; idx += 256) {
        int r = idx >> 5;
        int gr = rbase + r;
        float4 v = make_float4(0.f, 0.f, 0.f, 0.f);
        if (gr < nrows) v = ((const float4*)X)[(size_t)gr * 32 + (idx & 31)];
        ((float4*)Xs)[idx] = v;
    }
    __syncthreads();

    const int ct = t & 31;
    const int rt = t >> 5;
    float4 acc[8];
#pragma unroll
    for (int j = 0; j < 8; ++j) acc[j] = make_float4(0.f, 0.f, 0.f, 0.f);

    const float4* W4 = (const float4*)W;
    for (int k0 = 0; k0 < 128; k0 += 4) {
        float4 xk[8];
#pragma unroll
        for (int j = 0; j < 8; ++j)
            xk[j] = *(const float4*)&Xs[rt * 8 + j][k0];
#pragma unroll
        for (int kk = 0; kk < 4; ++kk) {
            float4 w = W4[(k0 + kk) * 32 + ct];
#pragma unroll
            for (int j = 0; j < 8; ++j) {
                float xv = (kk == 0) ? xk[j].x : (kk == 1) ? xk[j].y
                          : (kk == 2) ? xk[j].z : xk[j].w;
                acc[j].x += xv * w.x;
                acc[j].y += xv * w.y;
                acc[j].z += xv * w.z;
                acc[j].w += xv * w.w;
            }
        }
    }

#pragma unroll
    for (int j = 0; j < 8; ++j) {
        int r = rbase + rt * 8 + j;
        if (r < nrows) {
            float di = dinv[r];
            uint2 o;
            o.x = pk_bf16(acc[j].x * di, acc[j].y * di);
            o.y = pk_bf16(acc[j].z * di, acc[j].w * di);
            O[(size_t)r * 32 + ct] = o;
        }
    }
}

// ---------------- CSR aggregate (bf16 gather) ----------------

__global__ __launch_bounds__(256) void aggregate_kernel(const uint2* __restrict__ H2,
                                                        const int* __restrict__ rowptr,
                                                        const int* __restrict__ csr,
                                                        const float* __restrict__ dinv,
                                                        const float4* __restrict__ b4,
                                                        float4* __restrict__ out,
                                                        int relu) {
    int node = blockIdx.x * 4 + (threadIdx.x >> 6);
    if (node >= N_NODES) return;
    const int lane = threadIdx.x & 63;
    const int half = lane >> 5;
    const int col  = lane & 31;

    float4 acc = make_float4(0.f, 0.f, 0.f, 0.f);
    if (half == 0) {                      // self-loop term
        uint2 v = H2[(size_t)node * 32 + col];
        acc.x = bf_lo(v.x); acc.y = bf_hi(v.x);
        acc.z = bf_lo(v.y); acc.w = bf_hi(v.y);
    }

    int j = rowptr[node];
    const int end = rowptr[node + 1];

#define ACCUM(v) do { \
        acc.x += bf_lo((v).x); acc.y += bf_hi((v).x); \
        acc.z += bf_lo((v).y); acc.w += bf_hi((v).y); } while (0)

    for (; j + 16 <= end; j += 16) {
        int s0 = csr[j +  0 + half], s1 = csr[j +  2 + half];
        int s2 = csr[j +  4 + half], s3 = csr[j +  6 + half];
        int s4 = csr[j +  8 + half], s5 = csr[j + 10 + half];
        int s6 = csr[j + 12 + half], s7 = csr[j + 14 + half];
        uint2 v0 = H2[(size_t)s0 * 32 + col];
        uint2 v1 = H2[(size_t)s1 * 32 + col];
        uint2 v2 = H2[(size_t)s2 * 32 + col];
        uint2 v3 = H2[(size_t)s3 * 32 + col];
        uint2 v4 = H2[(size_t)s4 * 32 + col];
        uint2 v5 = H2[(size_t)s5 * 32 + col];
        uint2 v6 = H2[(size_t)s6 * 32 + col];
        uint2 v7 = H2[(size_t)s7 * 32 + col];
        ACCUM(v0); ACCUM(v1); ACCUM(v2); ACCUM(v3);
        ACCUM(v4); ACCUM(v5); ACCUM(v6); ACCUM(v7);
    }
    if (j + 8 <= end) {
        int s0 = csr[j + half], s1 = csr[j + 2 + half];
        int s2 = csr[j + 4 + half], s3 = csr[j + 6 + half];
        uint2 v0 = H2[(size_t)s0 * 32 + col];
        uint2 v1 = H2[(size_t)s1 * 32 + col];
        uint2 v2 = H2[(size_t)s2 * 32 + col];
        uint2 v3 = H2[(size_t)s3 * 32 + col];
        ACCUM(v0); ACCUM(v1); ACCUM(v2); ACCUM(v3);
        j += 8;
    }
    if (j + 4 <= end) {
        int s0 = csr[j + half], s1 = csr[j + 2 + half];
        uint2 v0 = H2[(size_t)s0 * 32 + col];
        uint2 v1 = H2[(size_t)s1 * 32 + col];
        ACCUM(v0); ACCUM(v1);
        j += 4;
    }
    if (j + 2 <= end) {
        int s = csr[j + half];
        uint2 v = H2[(size_t)s * 32 + col];
        ACCUM(v);
        j += 2;
    }
    if (j < end && half == 0) {
        int s = csr[j];
        uint2 v = H2[(size_t)s * 32 + col];
        ACCUM(v);
    }
#undef ACCUM

    acc.x += __shfl_xor(acc.x, 32, 64);
    acc.y += __shfl_xor(acc.y, 32, 64);
    acc.z += __shfl_xor(acc.z, 32, 64);
    acc.w += __shfl_xor(acc.w, 32, 64);

    if (half == 0) {
        float di = dinv[node];
        float4 bb = b4[col];
        float4 o;
        o.x = acc.x * di + bb.x;
        o.y = acc.y * di + bb.y;
        o.z = acc.z * di + bb.z;
        o.w = acc.w * di + bb.w;
        if (relu) {
            o.x = fmaxf(o.x, 0.f); o.y = fmaxf(o.y, 0.f);
            o.z = fmaxf(o.z, 0.f); o.w = fmaxf(o.w, 0.f);
        }
        out[(size_t)node * 32 + col] = o;
    }
}

// ---------------- launch ----------------

extern "C" void kernel_launch(void* const* d_in, const int* in_sizes, int n_in,
                              void* d_out, int out_size, void* d_ws, size_t ws_size,
                              hipStream_t stream) {
    const float* x  = (const float*)d_in[0];
    const int*   ei = (const int*)d_in[1];
    const float* W1 = (const float*)d_in[2];
    const float* b1 = (const float*)d_in[3];
    const float* W2 = (const float*)d_in[4];
    const float* b2 = (const float*)d_in[5];
    float* out = (float*)d_out;

    const int* src = ei;             // edge_index[0]
    const int* dst = ei + N_EDGES;   // edge_index[1]

    char* p = (char*)d_ws;
    int*      chist  = (int*)p;              p += GRID * 256 * 4;              // 200 KB
    float*    dinv   = (float*)p;            p += ((N_NODES * 4 + 1023) & ~1023);
    int*      rowptr = (int*)p;              p += (((N_NODES + 1) * 4 + 1023) & ~1023);
    unsigned* sorted = (unsigned*)p;         p += ((N_EDGES * 4 + 1023) & ~1023);
    int*      csr    = (int*)p;              p += ((N_EDGES * 4 + 1023) & ~1023);
    uint2*    hp     = (uint2*)p;            p += (size_t)N_NODES * DIM * 2;   // bf16 table
    float*    bufB   = (float*)p;                                              // fp32 h1

    const int gemmBlocks = (N_NODES + 63) / 64;   // 782
    const int aggBlocks  = (N_NODES + 3) / 4;     // 12500

    // ---- bucketed CSR build: 3 dispatches, zero global atomics, no memset ----
    chunk_hist<<<GRID, 256, 0, stream>>>(dst, chist);
    sort_scatter<<<GRID, 256, 0, stream>>>(src, dst, chist, sorted);
    csr_build<<<GRID, 256, 0, stream>>>(sorted, chist, rowptr, dinv, csr);

    // ---- layer 1: hp(bf16) = (x@W1)*dinv ; aggregate+bias+relu -> bufB(fp32) ----
    gemm_xw<<<gemmBlocks, 256, 0, stream>>>(x, W1, dinv, hp, N_NODES);
    aggregate_kernel<<<aggBlocks, 256, 0, stream>>>(hp, rowptr, csr, dinv,
                                                    (const float4*)b1, (float4*)bufB, 1);

    // ---- layer 2: hp(bf16) = (h1@W2)*dinv ; aggregate+bias -> out ----
    gemm_xw<<<gemmBlocks, 256, 0, stream>>>(bufB, W2, dinv, hp, N_NODES);
    aggregate_kernel<<<aggBlocks, 256, 0, stream>>>(hp, rowptr, csr, dinv,
                                                    (const float4*)b2, (float4*)out, 0);
}